// Round 10
// baseline (227.507 us; speedup 1.0000x reference)
//
#include <hip/hip_runtime.h>
#include <hip/hip_bf16.h>

// ---------------------------------------------------------------------------
// CrossAttention on MI355X (gfx950) — v16: v15's n-sliced-wave attn rebuilt
// on the PROVEN builtin only. PV's K=16 contraction is done as
// mfma_f32_16x16x32_bf16 with the upper 4 k-slots of each lane zeroed:
//   B lane(quad,l15): j=0..3 <- P[n=wave*16+quad*4+j][q=l15] (== S layout,
//   no redistribution), j=4..7 <- 0 ; A gets matching V values + zeros;
//   lac uses A = (1,1,1,1,0,0,0,0).
// No inline-asm MFMA (v15's NaN: asm MFMA bypasses compiler hazard nops).
// No forced occupancy bound (VGPR ~160 -> 3 blk/CU, no spills).
// Everything else identical to v14. 5 launches.
// ---------------------------------------------------------------------------

typedef unsigned short u16;
typedef __bf16 bf16x8 __attribute__((ext_vector_type(8)));
typedef float f32x4 __attribute__((ext_vector_type(4)));
typedef unsigned u32x2 __attribute__((ext_vector_type(2)));

extern "C" __device__ float __ocml_native_exp2_f32(float);

__device__ inline f32x4 mfma16(bf16x8 a, bf16x8 b, f32x4 c) {
    return __builtin_amdgcn_mfma_f32_16x16x32_bf16(a, b, c, 0, 0, 0);
}

__device__ inline u16 f2bf(float f) {
    union { float f; unsigned u; } v; v.f = f;
    unsigned r = v.u + 0x7fffu + ((v.u >> 16) & 1u);
    return (u16)(r >> 16);
}

// pack two f32 -> two bf16 in one u32 (a -> low16, b -> high16)
__device__ inline unsigned pk_bf16(float a, float b) {
    union { float f; unsigned u; } x, y; x.f = a; y.f = b;
    return __builtin_amdgcn_perm(y.u + 0x8000u, x.u + 0x8000u, 0x07060302u);
}

// single-instruction pack (RNE): D.lo = bf16(a), D.hi = bf16(b)
__device__ inline unsigned cvt_pk(float a, float b) {
    unsigned r;
    asm("v_cvt_pk_bf16_f32 %0, %1, %2" : "=v"(r) : "v"(a), "v"(b));
    return r;
}

// 4 packed bf16 in 2 u32 -> bf16x8 with upper 4 lanes zero (K=16-in-K=32 pad)
__device__ inline bf16x8 pad4(unsigned lo, unsigned hi) {
    union { unsigned u[4]; bf16x8 v; } t;
    t.u[0] = lo; t.u[1] = hi; t.u[2] = 0u; t.u[3] = 0u;
    return t.v;
}

__device__ inline void load_lds16(const void* g, void* l) {
    __builtin_amdgcn_global_load_lds(
        (const __attribute__((address_space(1))) void*)g,
        (__attribute__((address_space(3))) void*)l, 16, 0, 0);
}

// ---------------------------------------------------------------------------
// Fused: bf16 casts (text, Wq, Wk, Wo) + feature rows: full RMSNorm in-reg
// -> feats_bf normalized. Also zeroes qkss.
__global__ __launch_bounds__(256) void cast_rows_kernel(const float* __restrict__ text,
                                                        const float* __restrict__ Wq,
                                                        const float* __restrict__ Wk,
                                                        const float* __restrict__ Wo,
                                                        const float* __restrict__ features,
                                                        const float* __restrict__ g_feat,
                                                        u16* __restrict__ otext, u16* __restrict__ oWq,
                                                        u16* __restrict__ oWk, u16* __restrict__ oWo,
                                                        u16* __restrict__ feats_bf,
                                                        float* __restrict__ qkss) {
    int blk = blockIdx.x, tid = threadIdx.x;
    if (blk < 7168) {
        int i = blk * 256 + tid;
        const float* src; u16* dst; int off;
        if (i < 1048576)      { src = text; dst = otext; off = i; }
        else if (i < 1310720) { src = Wq;   dst = oWq;   off = i - 1048576; }
        else if (i < 1572864) { src = Wk;   dst = oWk;   off = i - 1310720; }
        else                  { src = Wo;   dst = oWo;   off = i - 1572864; }
        float4 v = ((const float4*)src)[off];
        uint2 p; p.x = pk_bf16(v.x, v.y); p.y = pk_bf16(v.z, v.w);
        ((uint2*)dst)[off] = p;
    } else {
        int i2 = (blk - 7168) * 256 + tid;
        if (i2 < 12288) qkss[i2] = 0.0f;     // zero Q/K row-ss accumulators
        int row = (blk - 7168) * 4 + (tid >> 6);
        int lane = tid & 63;
        const float4* rp = (const float4*)(features + (size_t)row * 1024) + lane * 4;
        float4 v[4];
        float ss = 0.0f;
        #pragma unroll
        for (int i = 0; i < 4; ++i) {
            v[i] = rp[i];
            ss += v[i].x * v[i].x + v[i].y * v[i].y + v[i].z * v[i].z + v[i].w * v[i].w;
        }
        #pragma unroll
        for (int m = 1; m < 64; m <<= 1) ss += __shfl_xor(ss, m, 64);
        float rs = rsqrtf(ss * (1.0f / 1024.0f) + 1e-6f);
        const float4* gp = (const float4*)(g_feat) + lane * 4;
        union { unsigned u[8]; uint4 q[2]; } ob;
        #pragma unroll
        for (int i = 0; i < 4; ++i) {
            float4 gv = gp[i];
            ob.u[i * 2]     = pk_bf16(v[i].x * rs * gv.x, v[i].y * rs * gv.y);
            ob.u[i * 2 + 1] = pk_bf16(v[i].z * rs * gv.z, v[i].w * rs * gv.w);
        }
        uint4* dst = (uint4*)(feats_bf + (size_t)row * 1024 + lane * 16);
        dst[0] = ob.q[0];
        dst[1] = ob.q[1];
    }
}

// ---------------------------------------------------------------------------
// normT: pure bf16 transpose feats_bf -> Vt via one 64x64 LDS tile.
__global__ __launch_bounds__(256) void normT_kernel(const u16* __restrict__ feats_bf,
                                                    u16* __restrict__ Vt) {
    __shared__ __align__(16) u16 tile[64][72];
    int tid = threadIdx.x, b = blockIdx.z;
    int n0 = blockIdx.x * 64, d0 = blockIdx.y * 64;
    int r = tid >> 2, cs = (tid & 3) * 16;
    int grow = b * 1024 + n0 + r;

    const uint4* src = (const uint4*)(feats_bf + (size_t)grow * 1024 + d0 + cs);
    union { u16 s[16]; uint4 v[2]; } ob;
    ob.v[0] = src[0];
    ob.v[1] = src[1];
    #pragma unroll
    for (int i = 0; i < 16; ++i) tile[r][cs + i] = ob.s[i];
    __syncthreads();
    union { u16 s[8]; uint4 v; } t0, t1;
    #pragma unroll
    for (int i = 0; i < 8; ++i) { t0.s[i] = tile[cs + i][r]; t1.s[i] = tile[cs + 8 + i][r]; }
    u16* tdst = Vt + ((size_t)(b * 1024 + d0 + r)) * 1024 + n0 + cs;
    *(uint4*)tdst = t0.v;
    *(uint4*)(tdst + 8) = t1.v;
}

// ---------------------------------------------------------------------------
// 128x64-tile GEMM, BK=64 — proven v10 structure (unchanged).
template <bool BF16OUT, bool NORM>
__device__ __forceinline__ void gemm64_bk64(const u16* __restrict__ A, const u16* __restrict__ B,
                                            const float* __restrict__ bias,
                                            const float* __restrict__ gvec,
                                            float* __restrict__ ssout,
                                            void* __restrict__ Cout,
                                            int m_blk, int n_blk, int K, int N,
                                            u16* As, u16* Bs) {
    int tid = threadIdx.x, wave = tid >> 6, lane = tid & 63;
    int quad = lane >> 4, l15 = lane & 15;
    int wm = wave & 1, wn = wave >> 1;
    int srl = lane >> 3, scl = lane & 7;
    const int swz = (scl ^ srl) * 8;     // pre-swizzled global chunk offset (u16)

    f32x4 acc[4][2] = {};

    auto stage = [&](int buf, int k0) {
        u16* Ad = As + buf * (128 * 64);
        u16* Bd = Bs + buf * (64 * 64);
        #pragma unroll
        for (int is = 0; is < 4; ++is) {
            int row = is * 32 + wave * 8 + srl;
            load_lds16(A + (size_t)(m_blk + row) * K + k0 + swz,
                       Ad + (is * 32 + wave * 8) * 64);
        }
        #pragma unroll
        for (int is = 0; is < 2; ++is) {
            int row = is * 32 + wave * 8 + srl;
            load_lds16(B + (size_t)(n_blk + row) * K + k0 + swz,
                       Bd + (is * 32 + wave * 8) * 64);
        }
    };

    stage(0, 0);
    __syncthreads();
    int cur = 0;

    for (int k0 = 0; k0 < K; k0 += 64) {
        if (k0 + 64 < K) stage(cur ^ 1, k0 + 64);   // prefetch next K-tile

        const u16* Ar = As + cur * (128 * 64);
        const u16* Br = Bs + cur * (64 * 64);
        #pragma unroll
        for (int kh = 0; kh < 2; ++kh) {
            bf16x8 af[4], bfr[2];
            int co = ((kh * 4 + quad) ^ (l15 & 7)) * 8;   // swizzled read chunk
            #pragma unroll
            for (int t = 0; t < 4; ++t)
                af[t] = *(const bf16x8*)&Ar[(wm * 64 + t * 16 + l15) * 64 + co];
            #pragma unroll
            for (int t = 0; t < 2; ++t)
                bfr[t] = *(const bf16x8*)&Br[(wn * 32 + t * 16 + l15) * 64 + co];
            #pragma unroll
            for (int mt = 0; mt < 4; ++mt)
                #pragma unroll
                for (int nt = 0; nt < 2; ++nt)
                    acc[mt][nt] = mfma16(af[mt], bfr[nt], acc[mt][nt]);
        }
        __syncthreads();
        cur ^= 1;
    }

    float bv[2], gv[2];
    #pragma unroll
    for (int nt = 0; nt < 2; ++nt) {
        int col = n_blk + wn * 32 + nt * 16 + l15;
        bv[nt] = bias[col];
        if (NORM) gv[nt] = gvec[col];
    }
    #pragma unroll
    for (int mt = 0; mt < 4; ++mt) {
        int row0 = m_blk + wm * 64 + mt * 16 + quad * 4;
        #pragma unroll
        for (int nt = 0; nt < 2; ++nt)
            #pragma unroll
            for (int r = 0; r < 4; ++r)
                acc[mt][nt][r] += bv[nt];
        if (NORM) {
            f32x4 ss4 = {0.0f, 0.0f, 0.0f, 0.0f};
            #pragma unroll
            for (int nt = 0; nt < 2; ++nt)
                #pragma unroll
                for (int r = 0; r < 4; ++r)
                    ss4[r] += acc[mt][nt][r] * acc[mt][nt][r];
            #pragma unroll
            for (int m = 1; m < 16; m <<= 1)
                #pragma unroll
                for (int r = 0; r < 4; ++r)
                    ss4[r] += __shfl_xor(ss4[r], m, 64);
            if (l15 == 0) {
                #pragma unroll
                for (int r = 0; r < 4; ++r)
                    atomicAdd(&ssout[row0 + r], ss4[r]);
            }
        }
        #pragma unroll
        for (int nt = 0; nt < 2; ++nt) {
            int col = n_blk + wn * 32 + nt * 16 + l15;
            #pragma unroll
            for (int r = 0; r < 4; ++r) {
                float val = NORM ? acc[mt][nt][r] * gv[nt] : acc[mt][nt][r];
                if (BF16OUT) ((u16*)Cout)[(size_t)(row0 + r) * N + col] = f2bf(val);
                else       ((float*)Cout)[(size_t)(row0 + r) * N + col] = val;
            }
        }
    }
}

__global__ __launch_bounds__(256) void gemm_qk_kernel(const u16* __restrict__ text_bf,
                                                      const u16* __restrict__ Wq,
                                                      const u16* __restrict__ feats_bf,
                                                      const u16* __restrict__ Wk,
                                                      const float* __restrict__ b_q,
                                                      const float* __restrict__ b_k,
                                                      const float* __restrict__ g_q,
                                                      const float* __restrict__ g_k,
                                                      float* __restrict__ qkss,
                                                      u16* __restrict__ QK) {
    __shared__ __align__(16) u16 As[2 * 128 * 64];
    __shared__ __align__(16) u16 Bs[2 * 64 * 64];
    int id = blockIdx.x;
    if (id < 512) {
        gemm64_bk64<true, true>(text_bf, Wq, b_q, g_q, qkss, QK,
                                (id & 31) * 128, (id >> 5) * 64, 1024, 1024, As, Bs);
    } else {
        id -= 512;
        gemm64_bk64<true, true>(feats_bf, Wk, b_k, g_k, qkss + 4096, QK + 4096 * 1024,
                                (id & 63) * 128, (id >> 6) * 64, 1024, 1024, As, Bs);
    }
}

__global__ __launch_bounds__(256) void gemm_o_kernel(const u16* __restrict__ A,
                                                     const u16* __restrict__ B,
                                                     const float* __restrict__ bias,
                                                     float* __restrict__ C) {
    __shared__ __align__(16) u16 As[2 * 128 * 64];
    __shared__ __align__(16) u16 Bs[2 * 64 * 64];
    int id = blockIdx.x;
    gemm64_bk64<false, false>(A, B, bias, nullptr, nullptr, C,
                              (id & 31) * 128, (id >> 5) * 64, 1024, 1024, As, Bs);
}

// ---------------------------------------------------------------------------
// Flash attention — v16: n-sliced waves (wave w owns n = w*16..w*16+15 of
// each 64-tile; q = all 64). Every K/V byte read from LDS once per block.
// P stays in registers; PV/lac use the K=32 builtin with upper-4 k-slots
// zeroed (exact K=16 contraction; k=quad*8+j maps j<4 -> n=wave*16+quad*4+j).
// Epilogue: 4-way cross-wave n-reduction via retired LDS.
__global__ __launch_bounds__(256) void attn_kernel(const u16* __restrict__ Q,
                                                   const u16* __restrict__ K,
                                                   const u16* __restrict__ Vt,
                                                   const float* __restrict__ qkss,
                                                   u16* __restrict__ Out) {
    const float QSCALE = 0.18033688011112042f;   // 0.125 * log2(e)
    int bh = blockIdx.x, qt = blockIdx.y;
    int b = bh >> 4, h = bh & 15;
    int tid = threadIdx.x, wave = tid >> 6, lane = tid & 63;
    int quad = lane >> 4, l15 = lane & 15;

    // LDS: [0,16K) Ks dbuf, [16K,32K) Vs dbuf; epilogue overlays the whole
    // region with R0[64][68] f32, R1[64][68] f32, lacb[4][64] f32 (35840B).
    __shared__ __align__(16) char smem[35840];
    u16* Ks = (u16*)smem;                 // [2][64*64]
    u16* Vs = Ks + 2 * 64 * 64;           // [2][64*64]

    // Q fragments (B-operand of 16x16x32) + per-row rs_q (QSCALE folded).
    bf16x8 qf[4][2];
    float rsq[4];
    #pragma unroll
    for (int mt = 0; mt < 4; ++mt) {
        int qrow = b * 512 + qt * 64 + mt * 16 + l15;
        const size_t qoff = (size_t)qrow * 1024 + h * 64 + quad * 8;
        qf[mt][0] = *(const bf16x8*)(Q + qoff);
        qf[mt][1] = *(const bf16x8*)(Q + qoff + 32);
        rsq[mt] = rsqrtf(qkss[qrow] * (1.0f / 1024.0f) + 1e-6f) * QSCALE;
    }
    const float* ssk = qkss + 4096 + b * 1024;

    int srl = lane >> 3, scl = lane & 7;
    const u16* Kbase = K + ((size_t)(b * 1024)) * 1024 + h * 64;
    const u16* Vbase = Vt + ((size_t)(b * 1024 + h * 64)) * 1024;

    const bf16x8 ones4 = pad4(0x3F803F80u, 0x3F803F80u);  // (1,1,1,1,0,0,0,0)

    f32x4 o[4][4] = {};      // O[d = dt*16+quad*4+r][q = mt*16+l15] partial
    f32x4 lac[4] = {};       // lac[mt][0] = denominator partial for q

    auto stage = [&](int buf, int n0) {
        #pragma unroll
        for (int j = 0; j < 2; ++j) {
            int row = wave * 16 + j * 8 + srl;
            load_lds16(Kbase + (size_t)(n0 + row) * 1024 + (scl ^ srl) * 8,
                       Ks + buf * 4096 + (wave * 16 + j * 8) * 64);
            load_lds16(Vbase + (size_t)row * 1024 + n0 + (scl ^ srl) * 8,
                       Vs + buf * 4096 + (wave * 16 + j * 8) * 64);
        }
    };

    stage(0, 0);
    __syncthreads();
    int cur = 0;

    const int vsw = (quad & 1) * 4;      // within-chunk u16 offset for V reads

    for (int n0 = 0; n0 < 1024; n0 += 64) {
        if (n0 < 960) stage(cur ^ 1, n0 + 64);   // prefetch next tile

        // QK^T: lane holds S[n = wave*16 + quad*4 + r][q = mt*16 + l15]
        f32x4 s[4];
        __builtin_amdgcn_s_setprio(1);
        {
            int R = wave * 16 + l15;
            int c1 = (quad ^ (l15 & 7)) * 8;
            bf16x8 kf0 = *(const bf16x8*)&Ks[cur * 4096 + R * 64 + c1];
            bf16x8 kf1 = *(const bf16x8*)&Ks[cur * 4096 + R * 64 + (c1 ^ 32)];
            #pragma unroll
            for (int mt = 0; mt < 4; ++mt) {
                f32x4 z = {0.0f, 0.0f, 0.0f, 0.0f};
                s[mt] = mfma16(kf0, qf[mt][0], z);
                s[mt] = mfma16(kf1, qf[mt][1], s[mt]);
            }
        }
        __builtin_amdgcn_s_setprio(0);

        // softmax numerator, fully in-register -> padded B fragments
        f32x4 kss = *(const f32x4*)&ssk[n0 + wave * 16 + quad * 4];
        f32x4 rsn;
        #pragma unroll
        for (int r = 0; r < 4; ++r)
            rsn[r] = rsqrtf(kss[r] * (1.0f / 1024.0f) + 1e-6f);
        bf16x8 pf[4];
        #pragma unroll
        for (int mt = 0; mt < 4; ++mt) {
            float e[4];
            #pragma unroll
            for (int r = 0; r < 4; ++r)
                e[r] = __ocml_native_exp2_f32(fmaf(s[mt][r], rsn[r] * rsq[mt], -16.0f));
            pf[mt] = pad4(cvt_pk(e[0], e[1]), cvt_pk(e[2], e[3]));
        }

        // V fragments (padded A-operand): V[d = dt*16+l15][n = wave*16+quad*4..+3]
        bf16x8 vf[4];
        #pragma unroll
        for (int dt = 0; dt < 4; ++dt) {
            int rowv = dt * 16 + l15;
            int ch = (wave * 2 + (quad >> 1)) ^ (l15 & 7);
            u32x2 vraw = *(const u32x2*)&Vs[cur * 4096 + rowv * 64 + ch * 8 + vsw];
            vf[dt] = pad4(vraw[0], vraw[1]);
        }

        __builtin_amdgcn_s_setprio(1);
        #pragma unroll
        for (int mt = 0; mt < 4; ++mt) {
            lac[mt] = mfma16(ones4, pf[mt], lac[mt]);
            #pragma unroll
            for (int dt = 0; dt < 4; ++dt)
                o[mt][dt] = mfma16(vf[dt], pf[mt], o[mt][dt]);
        }
        __builtin_amdgcn_s_setprio(0);

        __syncthreads();
        cur ^= 1;
    }

    // ---- 4-way cross-wave n-reduction through retired LDS ----
    float* R0   = (float*)smem;          // [64][68] (pad 4 -> conflict-light)
    float* R1   = R0 + 64 * 68;
    float* lacb = R1 + 64 * 68;          // [4][64]

    if (wave >= 2) {                     // step A: waves 2,3 dump partials
        float* R = (wave == 2) ? R0 : R1;
        #pragma unroll
        for (int mt = 0; mt < 4; ++mt) {
            #pragma unroll
            for (int dt = 0; dt < 4; ++dt)
                #pragma unroll
                for (int r = 0; r < 4; ++r)
                    R[(dt * 16 + quad * 4 + r) * 68 + mt * 16 + l15] = o[mt][dt][r];
            if (quad == 0) lacb[wave * 64 + mt * 16 + l15] = lac[mt][0];
        }
    }
    __syncthreads();
    if (wave < 2) {                      // step B: w0+=w2 -> R0, w1+=w3 -> R1
        float* R = (wave == 0) ? R0 : R1;
        #pragma unroll
        for (int mt = 0; mt < 4; ++mt) {
            #pragma unroll
            for (int dt = 0; dt < 4; ++dt)
                #pragma unroll
                for (int r = 0; r < 4; ++r) {
                    int ix = (dt * 16 + quad * 4 + r) * 68 + mt * 16 + l15;
                    R[ix] += o[mt][dt][r];
                }
            if (quad == 0)
                lacb[wave * 64 + mt * 16 + l15] =
                    lac[mt][0] + lacb[(wave + 2) * 64 + mt * 16 + l15];
        }
    }
    __syncthreads();
    // step C: lane owns q = wave*16+l15, d-range quad*16..+15
    {
        int q = wave * 16 + l15;
        float il = 1.0f / (lacb[q] + lacb[64 + q]);
        union { unsigned u[8]; uint4 v[2]; } pk;
        #pragma unroll
        for (int j = 0; j < 8; ++j) {
            int d0 = quad * 16 + 2 * j;
            float v0 = (R0[d0 * 68 + q] + R1[d0 * 68 + q]) * il;
            float v1 = (R0[(d0 + 1) * 68 + q] + R1[(d0 + 1) * 68 + q]) * il;
            pk.u[j] = cvt_pk(v0, v1);
        }
        size_t orow = ((size_t)(b * 512 + qt * 64 + q)) * 1024 + h * 64 + quad * 16;
        *(uint4*)(Out + orow) = pk.v[0];
        *(uint4*)(Out + orow + 8) = pk.v[1];
    }
}

// ---------------------------------------------------------------------------
extern "C" void kernel_launch(void* const* d_in, const int* in_sizes, int n_in,
                              void* d_out, int out_size, void* d_ws, size_t ws_size,
                              hipStream_t stream) {
    const float* text     = (const float*)d_in[0];
    const float* features = (const float*)d_in[1];
    const float* W_q      = (const float*)d_in[2];
    const float* b_q      = (const float*)d_in[3];
    const float* W_k      = (const float*)d_in[4];
    const float* b_k      = (const float*)d_in[5];
    const float* W_o      = (const float*)d_in[6];
    const float* b_o      = (const float*)d_in[7];
    const float* g_feat   = (const float*)d_in[8];
    const float* g_q      = (const float*)d_in[9];
    const float* g_k      = (const float*)d_in[10];

    char* ws = (char*)d_ws;
    u16*   text_bf  = (u16*)(ws + 0);            //  8 MB [4096,1024]
    u16*   Wq_bf    = (u16*)(ws + 8388608);      //  2 MB
    u16*   Wk_bf    = (u16*)(ws + 10485760);     //  2 MB
    u16*   Wo_bf    = (u16*)(ws + 12582912);     //  2 MB
    u16*   feats_bf = (u16*)(ws + 14680064);     // 16 MB [8192,1024] (normalized)
    u16*   Vt       = (u16*)(ws + 31457280);     // 16 MB [8][1024 d][1024 n]
    u16*   QKbuf    = (u16*)(ws + 48234496);     // 24 MB [12288,1024] (Q, then K)
    u16*   attn_bf  = (u16*)(ws + 73400320);     //  8 MB [4096,1024]
    float* qkss     = (float*)(ws + 81821696);   // 48 KB [12288] Q/K row ss

    // 1) casts + feature RMSNorm (full, in-reg) + qkss zero
    cast_rows_kernel<<<9216, 256, 0, stream>>>(text, W_q, W_k, W_o, features, g_feat,
                                               text_bf, Wq_bf, Wk_bf, Wo_bf,
                                               feats_bf, qkss);
    // 2) transpose feats_bf -> Vt
    normT_kernel<<<dim3(16, 16, 8), 256, 0, stream>>>(feats_bf, Vt);
    // 3) Q-proj + K-proj (g folded, row-ss atomics into qkss)
    gemm_qk_kernel<<<1536, 256, 0, stream>>>(text_bf, Wq_bf, feats_bf, Wk_bf,
                                             b_q, b_k, g_q, g_k, qkss, QKbuf);
    // 4) fused attention (applies rs_q / rs_n from qkss)
    attn_kernel<<<dim3(128, 8), 256, 0, stream>>>(QKbuf, QKbuf + 4096 * 1024, Vt, qkss, attn_bf);
    // 5) O-projection -> fp32 d_out
    gemm_o_kernel<<<512, 256, 0, stream>>>(attn_bf, Wo_bf, b_o, (float*)d_out);
}

// Round 11
// 212.798 us; speedup vs baseline: 1.0691x; 1.0691x over previous
//
#include <hip/hip_runtime.h>
#include <hip/hip_bf16.h>

// ---------------------------------------------------------------------------
// CrossAttention on MI355X (gfx950) — v17: v14 (best-proven per-kernel set)
// with attn reverted to v14's exact version (v16's K=16-padded PV was
// falsified: -53%) and normT MERGED into the gemm_qk launch (they are
// data-independent): gemm blocks id<1536, transpose blocks behind. Saves one
// launch gap AND lets normT's 22MB of pure-memory work ride in gemm_qk's
// spare HBM bandwidth (gemm is at 18% of peak). 4 launches.
// ---------------------------------------------------------------------------

typedef unsigned short u16;
typedef __bf16 bf16x8 __attribute__((ext_vector_type(8)));
typedef float f32x4 __attribute__((ext_vector_type(4)));

extern "C" __device__ float __ocml_native_exp2_f32(float);

__device__ inline f32x4 mfma16(bf16x8 a, bf16x8 b, f32x4 c) {
    return __builtin_amdgcn_mfma_f32_16x16x32_bf16(a, b, c, 0, 0, 0);
}

__device__ inline u16 f2bf(float f) {
    union { float f; unsigned u; } v; v.f = f;
    unsigned r = v.u + 0x7fffu + ((v.u >> 16) & 1u);
    return (u16)(r >> 16);
}

// pack two f32 -> two bf16 in one u32 (a -> low16, b -> high16)
__device__ inline unsigned pk_bf16(float a, float b) {
    union { float f; unsigned u; } x, y; x.f = a; y.f = b;
    return __builtin_amdgcn_perm(y.u + 0x8000u, x.u + 0x8000u, 0x07060302u);
}

// single-instruction pack (RNE): D.lo = bf16(a), D.hi = bf16(b)
__device__ inline unsigned cvt_pk(float a, float b) {
    unsigned r;
    asm("v_cvt_pk_bf16_f32 %0, %1, %2" : "=v"(r) : "v"(a), "v"(b));
    return r;
}

__device__ inline void load_lds16(const void* g, void* l) {
    __builtin_amdgcn_global_load_lds(
        (const __attribute__((address_space(1))) void*)g,
        (__attribute__((address_space(3))) void*)l, 16, 0, 0);
}

// ---------------------------------------------------------------------------
// Fused: bf16 casts (text, Wq, Wk, Wo) + feature rows: full RMSNorm in-reg
// -> feats_bf normalized. Also zeroes qkss.
__global__ __launch_bounds__(256) void cast_rows_kernel(const float* __restrict__ text,
                                                        const float* __restrict__ Wq,
                                                        const float* __restrict__ Wk,
                                                        const float* __restrict__ Wo,
                                                        const float* __restrict__ features,
                                                        const float* __restrict__ g_feat,
                                                        u16* __restrict__ otext, u16* __restrict__ oWq,
                                                        u16* __restrict__ oWk, u16* __restrict__ oWo,
                                                        u16* __restrict__ feats_bf,
                                                        float* __restrict__ qkss) {
    int blk = blockIdx.x, tid = threadIdx.x;
    if (blk < 7168) {
        int i = blk * 256 + tid;
        const float* src; u16* dst; int off;
        if (i < 1048576)      { src = text; dst = otext; off = i; }
        else if (i < 1310720) { src = Wq;   dst = oWq;   off = i - 1048576; }
        else if (i < 1572864) { src = Wk;   dst = oWk;   off = i - 1310720; }
        else                  { src = Wo;   dst = oWo;   off = i - 1572864; }
        float4 v = ((const float4*)src)[off];
        uint2 p; p.x = pk_bf16(v.x, v.y); p.y = pk_bf16(v.z, v.w);
        ((uint2*)dst)[off] = p;
    } else {
        int i2 = (blk - 7168) * 256 + tid;
        if (i2 < 12288) qkss[i2] = 0.0f;     // zero Q/K row-ss accumulators
        int row = (blk - 7168) * 4 + (tid >> 6);
        int lane = tid & 63;
        const float4* rp = (const float4*)(features + (size_t)row * 1024) + lane * 4;
        float4 v[4];
        float ss = 0.0f;
        #pragma unroll
        for (int i = 0; i < 4; ++i) {
            v[i] = rp[i];
            ss += v[i].x * v[i].x + v[i].y * v[i].y + v[i].z * v[i].z + v[i].w * v[i].w;
        }
        #pragma unroll
        for (int m = 1; m < 64; m <<= 1) ss += __shfl_xor(ss, m, 64);
        float rs = rsqrtf(ss * (1.0f / 1024.0f) + 1e-6f);
        const float4* gp = (const float4*)(g_feat) + lane * 4;
        union { unsigned u[8]; uint4 q[2]; } ob;
        #pragma unroll
        for (int i = 0; i < 4; ++i) {
            float4 gv = gp[i];
            ob.u[i * 2]     = pk_bf16(v[i].x * rs * gv.x, v[i].y * rs * gv.y);
            ob.u[i * 2 + 1] = pk_bf16(v[i].z * rs * gv.z, v[i].w * rs * gv.w);
        }
        uint4* dst = (uint4*)(feats_bf + (size_t)row * 1024 + lane * 16);
        dst[0] = ob.q[0];
        dst[1] = ob.q[1];
    }
}

// ---------------------------------------------------------------------------
// 128x64-tile GEMM, BK=64 — proven v10 structure (unchanged).
template <bool BF16OUT, bool NORM>
__device__ __forceinline__ void gemm64_bk64(const u16* __restrict__ A, const u16* __restrict__ B,
                                            const float* __restrict__ bias,
                                            const float* __restrict__ gvec,
                                            float* __restrict__ ssout,
                                            void* __restrict__ Cout,
                                            int m_blk, int n_blk, int K, int N,
                                            u16* As, u16* Bs) {
    int tid = threadIdx.x, wave = tid >> 6, lane = tid & 63;
    int quad = lane >> 4, l15 = lane & 15;
    int wm = wave & 1, wn = wave >> 1;
    int srl = lane >> 3, scl = lane & 7;
    const int swz = (scl ^ srl) * 8;     // pre-swizzled global chunk offset (u16)

    f32x4 acc[4][2] = {};

    auto stage = [&](int buf, int k0) {
        u16* Ad = As + buf * (128 * 64);
        u16* Bd = Bs + buf * (64 * 64);
        #pragma unroll
        for (int is = 0; is < 4; ++is) {
            int row = is * 32 + wave * 8 + srl;
            load_lds16(A + (size_t)(m_blk + row) * K + k0 + swz,
                       Ad + (is * 32 + wave * 8) * 64);
        }
        #pragma unroll
        for (int is = 0; is < 2; ++is) {
            int row = is * 32 + wave * 8 + srl;
            load_lds16(B + (size_t)(n_blk + row) * K + k0 + swz,
                       Bd + (is * 32 + wave * 8) * 64);
        }
    };

    stage(0, 0);
    __syncthreads();
    int cur = 0;

    for (int k0 = 0; k0 < K; k0 += 64) {
        if (k0 + 64 < K) stage(cur ^ 1, k0 + 64);   // prefetch next K-tile

        const u16* Ar = As + cur * (128 * 64);
        const u16* Br = Bs + cur * (64 * 64);
        #pragma unroll
        for (int kh = 0; kh < 2; ++kh) {
            bf16x8 af[4], bfr[2];
            int co = ((kh * 4 + quad) ^ (l15 & 7)) * 8;   // swizzled read chunk
            #pragma unroll
            for (int t = 0; t < 4; ++t)
                af[t] = *(const bf16x8*)&Ar[(wm * 64 + t * 16 + l15) * 64 + co];
            #pragma unroll
            for (int t = 0; t < 2; ++t)
                bfr[t] = *(const bf16x8*)&Br[(wn * 32 + t * 16 + l15) * 64 + co];
            #pragma unroll
            for (int mt = 0; mt < 4; ++mt)
                #pragma unroll
                for (int nt = 0; nt < 2; ++nt)
                    acc[mt][nt] = mfma16(af[mt], bfr[nt], acc[mt][nt]);
        }
        __syncthreads();
        cur ^= 1;
    }

    float bv[2], gv[2];
    #pragma unroll
    for (int nt = 0; nt < 2; ++nt) {
        int col = n_blk + wn * 32 + nt * 16 + l15;
        bv[nt] = bias[col];
        if (NORM) gv[nt] = gvec[col];
    }
    #pragma unroll
    for (int mt = 0; mt < 4; ++mt) {
        int row0 = m_blk + wm * 64 + mt * 16 + quad * 4;
        #pragma unroll
        for (int nt = 0; nt < 2; ++nt)
            #pragma unroll
            for (int r = 0; r < 4; ++r)
                acc[mt][nt][r] += bv[nt];
        if (NORM) {
            f32x4 ss4 = {0.0f, 0.0f, 0.0f, 0.0f};
            #pragma unroll
            for (int nt = 0; nt < 2; ++nt)
                #pragma unroll
                for (int r = 0; r < 4; ++r)
                    ss4[r] += acc[mt][nt][r] * acc[mt][nt][r];
            // reduce over the 16 lanes sharing this quad (masks 1..8 stay in l15)
            #pragma unroll
            for (int m = 1; m < 16; m <<= 1)
                #pragma unroll
                for (int r = 0; r < 4; ++r)
                    ss4[r] += __shfl_xor(ss4[r], m, 64);
            if (l15 == 0) {
                #pragma unroll
                for (int r = 0; r < 4; ++r)
                    atomicAdd(&ssout[row0 + r], ss4[r]);
            }
        }
        #pragma unroll
        for (int nt = 0; nt < 2; ++nt) {
            int col = n_blk + wn * 32 + nt * 16 + l15;
            #pragma unroll
            for (int r = 0; r < 4; ++r) {
                float val = NORM ? acc[mt][nt][r] * gv[nt] : acc[mt][nt][r];
                if (BF16OUT) ((u16*)Cout)[(size_t)(row0 + r) * N + col] = f2bf(val);
                else       ((float*)Cout)[(size_t)(row0 + r) * N + col] = val;
            }
        }
    }
}

// ---------------------------------------------------------------------------
// MERGED: Q-proj (512) + K-proj (1024) + feats transpose (2048 blocks).
// The transpose blocks are data-independent of the GEMM blocks and soak up
// the HBM bandwidth the GEMM leaves idle. GEMM blocks first (long pole).
__global__ __launch_bounds__(256) void gemm_qk_kernel(const u16* __restrict__ text_bf,
                                                      const u16* __restrict__ Wq,
                                                      const u16* __restrict__ feats_bf,
                                                      const u16* __restrict__ Wk,
                                                      const float* __restrict__ b_q,
                                                      const float* __restrict__ b_k,
                                                      const float* __restrict__ g_q,
                                                      const float* __restrict__ g_k,
                                                      float* __restrict__ qkss,
                                                      u16* __restrict__ QK,
                                                      u16* __restrict__ Vt) {
    __shared__ __align__(16) u16 As[2 * 128 * 64];
    __shared__ __align__(16) u16 Bs[2 * 64 * 64];
    int id = blockIdx.x;
    if (id < 512) {
        gemm64_bk64<true, true>(text_bf, Wq, b_q, g_q, qkss, QK,
                                (id & 31) * 128, (id >> 5) * 64, 1024, 1024, As, Bs);
    } else if (id < 1536) {
        id -= 512;
        gemm64_bk64<true, true>(feats_bf, Wk, b_k, g_k, qkss + 4096, QK + 4096 * 1024,
                                (id & 63) * 128, (id >> 6) * 64, 1024, 1024, As, Bs);
    } else {
        // transpose feats_bf -> Vt via one 64x64 LDS tile (aliases As)
        id -= 1536;
        int n0 = (id & 15) * 64, d0 = ((id >> 4) & 15) * 64, b = id >> 8;
        u16 (*tile)[72] = (u16(*)[72])As;
        int tid = threadIdx.x;
        int r = tid >> 2, cs = (tid & 3) * 16;
        int grow = b * 1024 + n0 + r;

        const uint4* src = (const uint4*)(feats_bf + (size_t)grow * 1024 + d0 + cs);
        union { u16 s[16]; uint4 v[2]; } ob;
        ob.v[0] = src[0];
        ob.v[1] = src[1];
        #pragma unroll
        for (int i = 0; i < 16; ++i) tile[r][cs + i] = ob.s[i];
        __syncthreads();
        union { u16 s[8]; uint4 v; } t0, t1;
        #pragma unroll
        for (int i = 0; i < 8; ++i) { t0.s[i] = tile[cs + i][r]; t1.s[i] = tile[cs + 8 + i][r]; }
        u16* tdst = Vt + ((size_t)(b * 1024 + d0 + r)) * 1024 + n0 + cs;
        *(uint4*)tdst = t0.v;
        *(uint4*)(tdst + 8) = t1.v;
    }
}

// O-projection, fp32 out (512 blocks)
__global__ __launch_bounds__(256) void gemm_o_kernel(const u16* __restrict__ A,
                                                     const u16* __restrict__ B,
                                                     const float* __restrict__ bias,
                                                     float* __restrict__ C) {
    __shared__ __align__(16) u16 As[2 * 128 * 64];
    __shared__ __align__(16) u16 Bs[2 * 64 * 64];
    int id = blockIdx.x;
    gemm64_bk64<false, false>(A, B, bias, nullptr, nullptr, C,
                              (id & 31) * 128, (id >> 5) * 64, 1024, 1024, As, Bs);
}

// ---------------------------------------------------------------------------
// Flash attention — v14's proven version: wave tiling (wq, wn), bilinear rs
// scaling from qkss, dbuf K/V, 40960B LDS -> 4 blocks/CU, cvt_pk packs.
__global__ __launch_bounds__(256, 4) void attn_kernel(const u16* __restrict__ Q,
                                                      const u16* __restrict__ K,
                                                      const u16* __restrict__ Vt,
                                                      const float* __restrict__ qkss,
                                                      u16* __restrict__ Out) {
    const float QSCALE = 0.18033688011112042f;   // 0.125 * log2(e)
    int bh = blockIdx.x, qt = blockIdx.y;
    int b = bh >> 4, h = bh & 15;
    int tid = threadIdx.x, wave = tid >> 6, lane = tid & 63;
    int quad = lane >> 4, l15 = lane & 15;
    int wq = wave & 1, wn = wave >> 1;

    __shared__ __align__(16) u16 Ks[2][64 * 64];
    __shared__ __align__(16) u16 Vs[2][64 * 64];
    __shared__ __align__(16) u16 Plds[4][2 * 16 * 32];   // [wave][mt][q=l15][n32]
    u16* Pw = &Plds[wave][0];
    const int pfs = (l15 >> 1) & 3;     // P swizzle key

    // Q fragments + per-row rs_q (QSCALE folded)
    bf16x8 qf[2][2];
    float rsq[2];
    #pragma unroll
    for (int mt = 0; mt < 2; ++mt) {
        int qrow = b * 512 + qt * 64 + wq * 32 + mt * 16 + l15;
        const size_t qoff = (size_t)qrow * 1024 + h * 64 + quad * 8;
        qf[mt][0] = *(const bf16x8*)(Q + qoff);
        qf[mt][1] = *(const bf16x8*)(Q + qoff + 32);
        rsq[mt] = rsqrtf(qkss[qrow] * (1.0f / 1024.0f) + 1e-6f) * QSCALE;
    }
    const float* ssk = qkss + 4096 + b * 1024;

    int srl = lane >> 3, scl = lane & 7;
    const u16* Kbase = K + ((size_t)(b * 1024)) * 1024 + h * 64;
    const u16* Vbase = Vt + ((size_t)(b * 1024 + h * 64)) * 1024;

    __bf16 onev = (__bf16)1.0f;
    bf16x8 ones = {onev, onev, onev, onev, onev, onev, onev, onev};

    f32x4 o[2][4] = {};
    f32x4 lac[2] = {{0.0f, 0.0f, 0.0f, 0.0f}, {0.0f, 0.0f, 0.0f, 0.0f}};

    auto stage = [&](int buf, int n0) {
        #pragma unroll
        for (int j = 0; j < 2; ++j) {
            int row = wave * 16 + j * 8 + srl;
            load_lds16(Kbase + (size_t)(n0 + row) * 1024 + (scl ^ srl) * 8,
                       &Ks[buf][(wave * 16 + j * 8) * 64]);
            load_lds16(Vbase + (size_t)row * 1024 + n0 + (scl ^ srl) * 8,
                       &Vs[buf][(wave * 16 + j * 8) * 64]);
        }
    };

    stage(0, 0);
    __syncthreads();
    int cur = 0;

    for (int n0 = 0; n0 < 1024; n0 += 64) {
        if (n0 < 960) stage(cur ^ 1, n0 + 64);   // prefetch next tile

        // QK^T (raw): s[mt][nt]: q = wq*32+mt*16+l15, n = wn*32+nt*16+quad*4+r
        f32x4 s[2][2];
        __builtin_amdgcn_s_setprio(1);
        #pragma unroll
        for (int nt = 0; nt < 2; ++nt) {
            int R = wn * 32 + nt * 16 + l15;
            int c1 = (quad ^ (l15 & 7)) * 8;
            bf16x8 kf0 = *(const bf16x8*)&Ks[cur][R * 64 + c1];
            bf16x8 kf1 = *(const bf16x8*)&Ks[cur][R * 64 + (c1 ^ 32)];
            #pragma unroll
            for (int mt = 0; mt < 2; ++mt) {
                f32x4 z = {0.0f, 0.0f, 0.0f, 0.0f};
                s[mt][nt] = mfma16(kf0, qf[mt][0], z);
                s[mt][nt] = mfma16(kf1, qf[mt][1], s[mt][nt]);
            }
        }
        __builtin_amdgcn_s_setprio(0);

        // softmax numerator with rs_n * rs_q scaling -> P (per-wave LDS, swizzled)
        #pragma unroll
        for (int nt = 0; nt < 2; ++nt) {
            int nb = n0 + wn * 32 + nt * 16 + quad * 4;
            f32x4 kss = *(const f32x4*)&ssk[nb];
            f32x4 rsn;
            #pragma unroll
            for (int r = 0; r < 4; ++r)
                rsn[r] = rsqrtf(kss[r] * (1.0f / 1024.0f) + 1e-6f);
            #pragma unroll
            for (int mt = 0; mt < 2; ++mt) {
                float e[4];
                #pragma unroll
                for (int r = 0; r < 4; ++r)
                    e[r] = __ocml_native_exp2_f32(fmaf(s[mt][nt][r], rsn[r] * rsq[mt], -16.0f));
                uint2 pk;
                pk.x = cvt_pk(e[0], e[1]);
                pk.y = cvt_pk(e[2], e[3]);
                *(uint2*)&Pw[mt * 512 + l15 * 32 + (((nt * 4 + quad) ^ (pfs << 1)) << 2)] = pk;
            }
        }

        // PV: o[mt][dt] += V[d, n-half] * P[n-half, q]
        bf16x8 pf[2], vf[4];
        #pragma unroll
        for (int mt = 0; mt < 2; ++mt)
            pf[mt] = *(const bf16x8*)&Pw[mt * 512 + l15 * 32 + ((quad ^ pfs) << 3)];
        #pragma unroll
        for (int dt = 0; dt < 4; ++dt) {
            int ch = ((wn * 4 + quad) ^ (l15 & 7)) * 8;
            vf[dt] = *(const bf16x8*)&Vs[cur][(dt * 16 + l15) * 64 + ch];
        }
        __builtin_amdgcn_s_setprio(1);
        #pragma unroll
        for (int mt = 0; mt < 2; ++mt) {
            lac[mt] = mfma16(ones, pf[mt], lac[mt]);
            #pragma unroll
            for (int dt = 0; dt < 4; ++dt)
                o[mt][dt] = mfma16(vf[dt], pf[mt], o[mt][dt]);
        }
        __builtin_amdgcn_s_setprio(0);

        __syncthreads();
        cur ^= 1;
    }

    // cross-wave (wn) reduction through retired K/V LDS
    float* Ored = (float*)&Ks[0][0];    // 16KB: [wq][lane][8 chunks of f32x4]
    float* Lred = (float*)&Vs[0][0];
    if (wn == 1) {
        #pragma unroll
        for (int mt = 0; mt < 2; ++mt) {
            #pragma unroll
            for (int dt = 0; dt < 4; ++dt) {
                int c = mt * 4 + dt;
                *(f32x4*)&Ored[wq * 2048 + lane * 32 + ((c ^ (lane & 7)) << 2)] = o[mt][dt];
            }
            Lred[wq * 128 + lane * 2 + mt] = lac[mt][0];
        }
    }
    __syncthreads();
    if (wn == 0) {
        #pragma unroll
        for (int mt = 0; mt < 2; ++mt) {
            float il = 1.0f / (lac[mt][0] + Lred[wq * 128 + lane * 2 + mt]);
            size_t obase =
                ((size_t)(b * 512 + qt * 64 + wq * 32 + mt * 16 + l15)) * 1024 + h * 64 + quad * 4;
            #pragma unroll
            for (int dt = 0; dt < 4; ++dt) {
                int c = mt * 4 + dt;
                f32x4 oo = o[mt][dt] + *(const f32x4*)&Ored[wq * 2048 + lane * 32 + ((c ^ (lane & 7)) << 2)];
                uint2 pk;
                pk.x = cvt_pk(oo[0] * il, oo[1] * il);
                pk.y = cvt_pk(oo[2] * il, oo[3] * il);
                *(uint2*)(Out + obase + dt * 16) = pk;
            }
        }
    }
}

// ---------------------------------------------------------------------------
extern "C" void kernel_launch(void* const* d_in, const int* in_sizes, int n_in,
                              void* d_out, int out_size, void* d_ws, size_t ws_size,
                              hipStream_t stream) {
    const float* text     = (const float*)d_in[0];
    const float* features = (const float*)d_in[1];
    const float* W_q      = (const float*)d_in[2];
    const float* b_q      = (const float*)d_in[3];
    const float* W_k      = (const float*)d_in[4];
    const float* b_k      = (const float*)d_in[5];
    const float* W_o      = (const float*)d_in[6];
    const float* b_o      = (const float*)d_in[7];
    const float* g_feat   = (const float*)d_in[8];
    const float* g_q      = (const float*)d_in[9];
    const float* g_k      = (const float*)d_in[10];

    char* ws = (char*)d_ws;
    u16*   text_bf  = (u16*)(ws + 0);            //  8 MB [4096,1024]
    u16*   Wq_bf    = (u16*)(ws + 8388608);      //  2 MB
    u16*   Wk_bf    = (u16*)(ws + 10485760);     //  2 MB
    u16*   Wo_bf    = (u16*)(ws + 12582912);     //  2 MB
    u16*   feats_bf = (u16*)(ws + 14680064);     // 16 MB [8192,1024] (normalized)
    u16*   Vt       = (u16*)(ws + 31457280);     // 16 MB [8][1024 d][1024 n]
    u16*   QKbuf    = (u16*)(ws + 48234496);     // 24 MB [12288,1024] (Q, then K)
    u16*   attn_bf  = (u16*)(ws + 73400320);     //  8 MB [4096,1024]
    float* qkss     = (float*)(ws + 81821696);   // 48 KB [12288] Q/K row ss

    // 1) casts + feature RMSNorm (full, in-reg) + qkss zero
    cast_rows_kernel<<<9216, 256, 0, stream>>>(text, W_q, W_k, W_o, features, g_feat,
                                               text_bf, Wq_bf, Wk_bf, Wo_bf,
                                               feats_bf, qkss);
    // 2) Q-proj + K-proj (g folded, row-ss atomics) MERGED with feats->Vt transpose
    gemm_qk_kernel<<<3584, 256, 0, stream>>>(text_bf, Wq_bf, feats_bf, Wk_bf,
                                             b_q, b_k, g_q, g_k, qkss, QKbuf, Vt);
    // 3) fused attention (applies rs_q / rs_n from qkss)
    attn_kernel<<<dim3(128, 8), 256, 0, stream>>>(QKbuf, QKbuf + 4096 * 1024, Vt, qkss, attn_bf);
    // 4) O-projection -> fp32 d_out
    gemm_o_kernel<<<512, 256, 0, stream>>>(attn_bf, Wo_bf, b_o, (float*)d_out);
}

// Round 13
// 209.725 us; speedup vs baseline: 1.0848x; 1.0147x over previous
//
#include <hip/hip_runtime.h>
#include <hip/hip_bf16.h>

// ---------------------------------------------------------------------------
// CrossAttention on MI355X (gfx950) — v19: v17 + attn widened to 8 waves
// (512 threads, 128 q rows/block, grid.y 8->4). Per-wave inner code is
// VERBATIM v14/v17 (mt=2, 32q x 32n per wave). Only changes: wave->(wq,wn)
// decomposition (wq=wave>>1 in [0,4), wn=wave&1), staging 8 rows/wave,
// Pw stride, epilogue wq range (Ored = 4x8KB over retired K/V LDS, Lred at
// Plds base). Staging issues + barriers per unit work halve. 4 launches.
// ---------------------------------------------------------------------------

typedef unsigned short u16;
typedef __bf16 bf16x8 __attribute__((ext_vector_type(8)));
typedef float f32x4 __attribute__((ext_vector_type(4)));

extern "C" __device__ float __ocml_native_exp2_f32(float);

__device__ inline f32x4 mfma16(bf16x8 a, bf16x8 b, f32x4 c) {
    return __builtin_amdgcn_mfma_f32_16x16x32_bf16(a, b, c, 0, 0, 0);
}

__device__ inline u16 f2bf(float f) {
    union { float f; unsigned u; } v; v.f = f;
    unsigned r = v.u + 0x7fffu + ((v.u >> 16) & 1u);
    return (u16)(r >> 16);
}

// pack two f32 -> two bf16 in one u32 (a -> low16, b -> high16)
__device__ inline unsigned pk_bf16(float a, float b) {
    union { float f; unsigned u; } x, y; x.f = a; y.f = b;
    return __builtin_amdgcn_perm(y.u + 0x8000u, x.u + 0x8000u, 0x07060302u);
}

// single-instruction pack (RNE): D.lo = bf16(a), D.hi = bf16(b)
__device__ inline unsigned cvt_pk(float a, float b) {
    unsigned r;
    asm("v_cvt_pk_bf16_f32 %0, %1, %2" : "=v"(r) : "v"(a), "v"(b));
    return r;
}

__device__ inline void load_lds16(const void* g, void* l) {
    __builtin_amdgcn_global_load_lds(
        (const __attribute__((address_space(1))) void*)g,
        (__attribute__((address_space(3))) void*)l, 16, 0, 0);
}

// ---------------------------------------------------------------------------
// Fused: bf16 casts (text, Wq, Wk, Wo) + feature rows: full RMSNorm in-reg
// -> feats_bf normalized. Also zeroes qkss.
__global__ __launch_bounds__(256) void cast_rows_kernel(const float* __restrict__ text,
                                                        const float* __restrict__ Wq,
                                                        const float* __restrict__ Wk,
                                                        const float* __restrict__ Wo,
                                                        const float* __restrict__ features,
                                                        const float* __restrict__ g_feat,
                                                        u16* __restrict__ otext, u16* __restrict__ oWq,
                                                        u16* __restrict__ oWk, u16* __restrict__ oWo,
                                                        u16* __restrict__ feats_bf,
                                                        float* __restrict__ qkss) {
    int blk = blockIdx.x, tid = threadIdx.x;
    if (blk < 7168) {
        int i = blk * 256 + tid;
        const float* src; u16* dst; int off;
        if (i < 1048576)      { src = text; dst = otext; off = i; }
        else if (i < 1310720) { src = Wq;   dst = oWq;   off = i - 1048576; }
        else if (i < 1572864) { src = Wk;   dst = oWk;   off = i - 1310720; }
        else                  { src = Wo;   dst = oWo;   off = i - 1572864; }
        float4 v = ((const float4*)src)[off];
        uint2 p; p.x = pk_bf16(v.x, v.y); p.y = pk_bf16(v.z, v.w);
        ((uint2*)dst)[off] = p;
    } else {
        int i2 = (blk - 7168) * 256 + tid;
        if (i2 < 12288) qkss[i2] = 0.0f;     // zero Q/K row-ss accumulators
        int row = (blk - 7168) * 4 + (tid >> 6);
        int lane = tid & 63;
        const float4* rp = (const float4*)(features + (size_t)row * 1024) + lane * 4;
        float4 v[4];
        float ss = 0.0f;
        #pragma unroll
        for (int i = 0; i < 4; ++i) {
            v[i] = rp[i];
            ss += v[i].x * v[i].x + v[i].y * v[i].y + v[i].z * v[i].z + v[i].w * v[i].w;
        }
        #pragma unroll
        for (int m = 1; m < 64; m <<= 1) ss += __shfl_xor(ss, m, 64);
        float rs = rsqrtf(ss * (1.0f / 1024.0f) + 1e-6f);
        const float4* gp = (const float4*)(g_feat) + lane * 4;
        union { unsigned u[8]; uint4 q[2]; } ob;
        #pragma unroll
        for (int i = 0; i < 4; ++i) {
            float4 gv = gp[i];
            ob.u[i * 2]     = pk_bf16(v[i].x * rs * gv.x, v[i].y * rs * gv.y);
            ob.u[i * 2 + 1] = pk_bf16(v[i].z * rs * gv.z, v[i].w * rs * gv.w);
        }
        uint4* dst = (uint4*)(feats_bf + (size_t)row * 1024 + lane * 16);
        dst[0] = ob.q[0];
        dst[1] = ob.q[1];
    }
}

// ---------------------------------------------------------------------------
// 128x64-tile GEMM, BK=64 — proven v10 structure (unchanged).
template <bool BF16OUT, bool NORM>
__device__ __forceinline__ void gemm64_bk64(const u16* __restrict__ A, const u16* __restrict__ B,
                                            const float* __restrict__ bias,
                                            const float* __restrict__ gvec,
                                            float* __restrict__ ssout,
                                            void* __restrict__ Cout,
                                            int m_blk, int n_blk, int K, int N,
                                            u16* As, u16* Bs) {
    int tid = threadIdx.x, wave = tid >> 6, lane = tid & 63;
    int quad = lane >> 4, l15 = lane & 15;
    int wm = wave & 1, wn = wave >> 1;
    int srl = lane >> 3, scl = lane & 7;
    const int swz = (scl ^ srl) * 8;     // pre-swizzled global chunk offset (u16)

    f32x4 acc[4][2] = {};

    auto stage = [&](int buf, int k0) {
        u16* Ad = As + buf * (128 * 64);
        u16* Bd = Bs + buf * (64 * 64);
        #pragma unroll
        for (int is = 0; is < 4; ++is) {
            int row = is * 32 + wave * 8 + srl;
            load_lds16(A + (size_t)(m_blk + row) * K + k0 + swz,
                       Ad + (is * 32 + wave * 8) * 64);
        }
        #pragma unroll
        for (int is = 0; is < 2; ++is) {
            int row = is * 32 + wave * 8 + srl;
            load_lds16(B + (size_t)(n_blk + row) * K + k0 + swz,
                       Bd + (is * 32 + wave * 8) * 64);
        }
    };

    stage(0, 0);
    __syncthreads();
    int cur = 0;

    for (int k0 = 0; k0 < K; k0 += 64) {
        if (k0 + 64 < K) stage(cur ^ 1, k0 + 64);   // prefetch next K-tile

        const u16* Ar = As + cur * (128 * 64);
        const u16* Br = Bs + cur * (64 * 64);
        #pragma unroll
        for (int kh = 0; kh < 2; ++kh) {
            bf16x8 af[4], bfr[2];
            int co = ((kh * 4 + quad) ^ (l15 & 7)) * 8;   // swizzled read chunk
            #pragma unroll
            for (int t = 0; t < 4; ++t)
                af[t] = *(const bf16x8*)&Ar[(wm * 64 + t * 16 + l15) * 64 + co];
            #pragma unroll
            for (int t = 0; t < 2; ++t)
                bfr[t] = *(const bf16x8*)&Br[(wn * 32 + t * 16 + l15) * 64 + co];
            #pragma unroll
            for (int mt = 0; mt < 4; ++mt)
                #pragma unroll
                for (int nt = 0; nt < 2; ++nt)
                    acc[mt][nt] = mfma16(af[mt], bfr[nt], acc[mt][nt]);
        }
        __syncthreads();
        cur ^= 1;
    }

    float bv[2], gv[2];
    #pragma unroll
    for (int nt = 0; nt < 2; ++nt) {
        int col = n_blk + wn * 32 + nt * 16 + l15;
        bv[nt] = bias[col];
        if (NORM) gv[nt] = gvec[col];
    }
    #pragma unroll
    for (int mt = 0; mt < 4; ++mt) {
        int row0 = m_blk + wm * 64 + mt * 16 + quad * 4;
        #pragma unroll
        for (int nt = 0; nt < 2; ++nt)
            #pragma unroll
            for (int r = 0; r < 4; ++r)
                acc[mt][nt][r] += bv[nt];
        if (NORM) {
            f32x4 ss4 = {0.0f, 0.0f, 0.0f, 0.0f};
            #pragma unroll
            for (int nt = 0; nt < 2; ++nt)
                #pragma unroll
                for (int r = 0; r < 4; ++r)
                    ss4[r] += acc[mt][nt][r] * acc[mt][nt][r];
            // reduce over the 16 lanes sharing this quad (masks 1..8 stay in l15)
            #pragma unroll
            for (int m = 1; m < 16; m <<= 1)
                #pragma unroll
                for (int r = 0; r < 4; ++r)
                    ss4[r] += __shfl_xor(ss4[r], m, 64);
            if (l15 == 0) {
                #pragma unroll
                for (int r = 0; r < 4; ++r)
                    atomicAdd(&ssout[row0 + r], ss4[r]);
            }
        }
        #pragma unroll
        for (int nt = 0; nt < 2; ++nt) {
            int col = n_blk + wn * 32 + nt * 16 + l15;
            #pragma unroll
            for (int r = 0; r < 4; ++r) {
                float val = NORM ? acc[mt][nt][r] * gv[nt] : acc[mt][nt][r];
                if (BF16OUT) ((u16*)Cout)[(size_t)(row0 + r) * N + col] = f2bf(val);
                else       ((float*)Cout)[(size_t)(row0 + r) * N + col] = val;
            }
        }
    }
}

// ---------------------------------------------------------------------------
// MERGED: Q-proj (512) + K-proj (1024) + feats transpose (2048 blocks).
__global__ __launch_bounds__(256) void gemm_qk_kernel(const u16* __restrict__ text_bf,
                                                      const u16* __restrict__ Wq,
                                                      const u16* __restrict__ feats_bf,
                                                      const u16* __restrict__ Wk,
                                                      const float* __restrict__ b_q,
                                                      const float* __restrict__ b_k,
                                                      const float* __restrict__ g_q,
                                                      const float* __restrict__ g_k,
                                                      float* __restrict__ qkss,
                                                      u16* __restrict__ QK,
                                                      u16* __restrict__ Vt) {
    __shared__ __align__(16) u16 As[2 * 128 * 64];
    __shared__ __align__(16) u16 Bs[2 * 64 * 64];
    int id = blockIdx.x;
    if (id < 512) {
        gemm64_bk64<true, true>(text_bf, Wq, b_q, g_q, qkss, QK,
                                (id & 31) * 128, (id >> 5) * 64, 1024, 1024, As, Bs);
    } else if (id < 1536) {
        id -= 512;
        gemm64_bk64<true, true>(feats_bf, Wk, b_k, g_k, qkss + 4096, QK + 4096 * 1024,
                                (id & 63) * 128, (id >> 6) * 64, 1024, 1024, As, Bs);
    } else {
        // transpose feats_bf -> Vt via one 64x64 LDS tile (aliases As)
        id -= 1536;
        int n0 = (id & 15) * 64, d0 = ((id >> 4) & 15) * 64, b = id >> 8;
        u16 (*tile)[72] = (u16(*)[72])As;
        int tid = threadIdx.x;
        int r = tid >> 2, cs = (tid & 3) * 16;
        int grow = b * 1024 + n0 + r;

        const uint4* src = (const uint4*)(feats_bf + (size_t)grow * 1024 + d0 + cs);
        union { u16 s[16]; uint4 v[2]; } ob;
        ob.v[0] = src[0];
        ob.v[1] = src[1];
        #pragma unroll
        for (int i = 0; i < 16; ++i) tile[r][cs + i] = ob.s[i];
        __syncthreads();
        union { u16 s[8]; uint4 v; } t0, t1;
        #pragma unroll
        for (int i = 0; i < 8; ++i) { t0.s[i] = tile[cs + i][r]; t1.s[i] = tile[cs + 8 + i][r]; }
        u16* tdst = Vt + ((size_t)(b * 1024 + d0 + r)) * 1024 + n0 + cs;
        *(uint4*)tdst = t0.v;
        *(uint4*)(tdst + 8) = t1.v;
    }
}

// O-projection, fp32 out (512 blocks)
__global__ __launch_bounds__(256) void gemm_o_kernel(const u16* __restrict__ A,
                                                     const u16* __restrict__ B,
                                                     const float* __restrict__ bias,
                                                     float* __restrict__ C) {
    __shared__ __align__(16) u16 As[2 * 128 * 64];
    __shared__ __align__(16) u16 Bs[2 * 64 * 64];
    int id = blockIdx.x;
    gemm64_bk64<false, false>(A, B, bias, nullptr, nullptr, C,
                              (id & 31) * 128, (id >> 5) * 64, 1024, 1024, As, Bs);
}

// ---------------------------------------------------------------------------
// Flash attention — v19: 8 waves (512 thr), 128 q rows/block, grid.y = 4.
// wq = wave>>1 in [0,4) picks 32 q rows; wn = wave&1 picks the 32-n half.
// Per-wave inner code verbatim v14/v17. Staging: 8 rows/wave (1 K + 1 V
// issue). LDS: Ks 16K + Vs 16K + Plds 8x2KB = 48KB. Epilogue: v14 code with
// wq in [0,4) (Ored = 4x8KB over retired K/V, Lred at Plds base).
__global__ __launch_bounds__(512) void attn_kernel(const u16* __restrict__ Q,
                                                   const u16* __restrict__ K,
                                                   const u16* __restrict__ Vt,
                                                   const float* __restrict__ qkss,
                                                   u16* __restrict__ Out) {
    const float QSCALE = 0.18033688011112042f;   // 0.125 * log2(e)
    int bh = blockIdx.x, qt = blockIdx.y;
    int b = bh >> 4, h = bh & 15;
    int tid = threadIdx.x, wave = tid >> 6, lane = tid & 63;
    int quad = lane >> 4, l15 = lane & 15;
    int wq = wave >> 1, wn = wave & 1;

    __shared__ __align__(16) char smem[49152];
    u16* Ks = (u16*)smem;                 // [2][64*64]
    u16* Vs = Ks + 8192;                  // [2][64*64]
    u16* Plds = Vs + 8192;                // [8 waves][2*16*32]
    u16* Pw = Plds + wave * 1024;
    const int pfs = (l15 >> 1) & 3;       // P swizzle key

    // Q fragments + per-row rs_q (QSCALE folded). q = qt*128 + wq*32 + mt*16 + l15
    bf16x8 qf[2][2];
    float rsq[2];
    #pragma unroll
    for (int mt = 0; mt < 2; ++mt) {
        int qrow = b * 512 + qt * 128 + wq * 32 + mt * 16 + l15;
        const size_t qoff = (size_t)qrow * 1024 + h * 64 + quad * 8;
        qf[mt][0] = *(const bf16x8*)(Q + qoff);
        qf[mt][1] = *(const bf16x8*)(Q + qoff + 32);
        rsq[mt] = rsqrtf(qkss[qrow] * (1.0f / 1024.0f) + 1e-6f) * QSCALE;
    }
    const float* ssk = qkss + 4096 + b * 1024;

    int srl = lane >> 3, scl = lane & 7;
    const u16* Kbase = K + ((size_t)(b * 1024)) * 1024 + h * 64;
    const u16* Vbase = Vt + ((size_t)(b * 1024 + h * 64)) * 1024;

    __bf16 onev = (__bf16)1.0f;
    bf16x8 ones = {onev, onev, onev, onev, onev, onev, onev, onev};

    f32x4 o[2][4] = {};
    f32x4 lac[2] = {{0.0f, 0.0f, 0.0f, 0.0f}, {0.0f, 0.0f, 0.0f, 0.0f}};

    // stage one 64-row K/V chunk: 8 waves x 8 rows each (1 K + 1 V issue/wave)
    auto stage = [&](int buf, int n0) {
        int row = wave * 8 + srl;          // row & 7 == srl (swizzle invariant)
        load_lds16(Kbase + (size_t)(n0 + row) * 1024 + (scl ^ srl) * 8,
                   Ks + buf * 4096 + (wave * 8) * 64);
        load_lds16(Vbase + (size_t)row * 1024 + n0 + (scl ^ srl) * 8,
                   Vs + buf * 4096 + (wave * 8) * 64);
    };

    stage(0, 0);
    __syncthreads();
    int cur = 0;

    for (int n0 = 0; n0 < 1024; n0 += 64) {
        if (n0 < 960) stage(cur ^ 1, n0 + 64);   // prefetch next tile

        // QK^T (raw): s[mt][nt]: q = qt*128+wq*32+mt*16+l15, n = wn*32+nt*16+quad*4+r
        f32x4 s[2][2];
        __builtin_amdgcn_s_setprio(1);
        #pragma unroll
        for (int nt = 0; nt < 2; ++nt) {
            int R = wn * 32 + nt * 16 + l15;
            int c1 = (quad ^ (l15 & 7)) * 8;
            bf16x8 kf0 = *(const bf16x8*)&Ks[cur * 4096 + R * 64 + c1];
            bf16x8 kf1 = *(const bf16x8*)&Ks[cur * 4096 + R * 64 + (c1 ^ 32)];
            #pragma unroll
            for (int mt = 0; mt < 2; ++mt) {
                f32x4 z = {0.0f, 0.0f, 0.0f, 0.0f};
                s[mt][nt] = mfma16(kf0, qf[mt][0], z);
                s[mt][nt] = mfma16(kf1, qf[mt][1], s[mt][nt]);
            }
        }
        __builtin_amdgcn_s_setprio(0);

        // softmax numerator with rs_n * rs_q scaling -> P (per-wave LDS, swizzled)
        #pragma unroll
        for (int nt = 0; nt < 2; ++nt) {
            int nb = n0 + wn * 32 + nt * 16 + quad * 4;
            f32x4 kss = *(const f32x4*)&ssk[nb];
            f32x4 rsn;
            #pragma unroll
            for (int r = 0; r < 4; ++r)
                rsn[r] = rsqrtf(kss[r] * (1.0f / 1024.0f) + 1e-6f);
            #pragma unroll
            for (int mt = 0; mt < 2; ++mt) {
                float e[4];
                #pragma unroll
                for (int r = 0; r < 4; ++r)
                    e[r] = __ocml_native_exp2_f32(fmaf(s[mt][nt][r], rsn[r] * rsq[mt], -16.0f));
                uint2 pk;
                pk.x = cvt_pk(e[0], e[1]);
                pk.y = cvt_pk(e[2], e[3]);
                *(uint2*)&Pw[mt * 512 + l15 * 32 + (((nt * 4 + quad) ^ (pfs << 1)) << 2)] = pk;
            }
        }

        // PV: o[mt][dt] += V[d, n-half] * P[n-half, q]
        bf16x8 pf[2], vf[4];
        #pragma unroll
        for (int mt = 0; mt < 2; ++mt)
            pf[mt] = *(const bf16x8*)&Pw[mt * 512 + l15 * 32 + ((quad ^ pfs) << 3)];
        #pragma unroll
        for (int dt = 0; dt < 4; ++dt) {
            int ch = ((wn * 4 + quad) ^ (l15 & 7)) * 8;
            vf[dt] = *(const bf16x8*)&Vs[cur * 4096 + (dt * 16 + l15) * 64 + ch];
        }
        __builtin_amdgcn_s_setprio(1);
        #pragma unroll
        for (int mt = 0; mt < 2; ++mt) {
            lac[mt] = mfma16(ones, pf[mt], lac[mt]);
            #pragma unroll
            for (int dt = 0; dt < 4; ++dt)
                o[mt][dt] = mfma16(vf[dt], pf[mt], o[mt][dt]);
        }
        __builtin_amdgcn_s_setprio(0);

        __syncthreads();
        cur ^= 1;
    }

    // cross-wave (wn) reduction through retired K/V LDS (v14 code, wq in [0,4))
    float* Ored = (float*)smem;           // [wq][lane][8 chunks of f32x4] = 32KB
    float* Lred = (float*)(smem + 32768); // [wq][lane*2+mt] floats (2KB, Plds base)
    if (wn == 1) {
        #pragma unroll
        for (int mt = 0; mt < 2; ++mt) {
            #pragma unroll
            for (int dt = 0; dt < 4; ++dt) {
                int c = mt * 4 + dt;
                *(f32x4*)&Ored[wq * 2048 + lane * 32 + ((c ^ (lane & 7)) << 2)] = o[mt][dt];
            }
            Lred[wq * 128 + lane * 2 + mt] = lac[mt][0];
        }
    }
    __syncthreads();
    if (wn == 0) {
        #pragma unroll
        for (int mt = 0; mt < 2; ++mt) {
            float il = 1.0f / (lac[mt][0] + Lred[wq * 128 + lane * 2 + mt]);
            size_t obase =
                ((size_t)(b * 512 + qt * 128 + wq * 32 + mt * 16 + l15)) * 1024 + h * 64 + quad * 4;
            #pragma unroll
            for (int dt = 0; dt < 4; ++dt) {
                int c = mt * 4 + dt;
                f32x4 oo = o[mt][dt] + *(const f32x4*)&Ored[wq * 2048 + lane * 32 + ((c ^ (lane & 7)) << 2)];
                uint2 pk;
                pk.x = cvt_pk(oo[0] * il, oo[1] * il);
                pk.y = cvt_pk(oo[2] * il, oo[3] * il);
                *(uint2*)(Out + obase + dt * 16) = pk;
            }
        }
    }
}

// ---------------------------------------------------------------------------
extern "C" void kernel_launch(void* const* d_in, const int* in_sizes, int n_in,
                              void* d_out, int out_size, void* d_ws, size_t ws_size,
                              hipStream_t stream) {
    const float* text     = (const float*)d_in[0];
    const float* features = (const float*)d_in[1];
    const float* W_q      = (const float*)d_in[2];
    const float* b_q      = (const float*)d_in[3];
    const float* W_k      = (const float*)d_in[4];
    const float* b_k      = (const float*)d_in[5];
    const float* W_o      = (const float*)d_in[6];
    const float* b_o      = (const float*)d_in[7];
    const float* g_feat   = (const float*)d_in[8];
    const float* g_q      = (const float*)d_in[9];
    const float* g_k      = (const float*)d_in[10];

    char* ws = (char*)d_ws;
    u16*   text_bf  = (u16*)(ws + 0);            //  8 MB [4096,1024]
    u16*   Wq_bf    = (u16*)(ws + 8388608);      //  2 MB
    u16*   Wk_bf    = (u16*)(ws + 10485760);     //  2 MB
    u16*   Wo_bf    = (u16*)(ws + 12582912);     //  2 MB
    u16*   feats_bf = (u16*)(ws + 14680064);     // 16 MB [8192,1024] (normalized)
    u16*   Vt       = (u16*)(ws + 31457280);     // 16 MB [8][1024 d][1024 n]
    u16*   QKbuf    = (u16*)(ws + 48234496);     // 24 MB [12288,1024] (Q, then K)
    u16*   attn_bf  = (u16*)(ws + 73400320);     //  8 MB [4096,1024]
    float* qkss     = (float*)(ws + 81821696);   // 48 KB [12288] Q/K row ss

    // 1) casts + feature RMSNorm (full, in-reg) + qkss zero
    cast_rows_kernel<<<9216, 256, 0, stream>>>(text, W_q, W_k, W_o, features, g_feat,
                                               text_bf, Wq_bf, Wk_bf, Wo_bf,
                                               feats_bf, qkss);
    // 2) Q-proj + K-proj (g folded, row-ss atomics) MERGED with feats->Vt transpose
    gemm_qk_kernel<<<3584, 256, 0, stream>>>(text_bf, Wq_bf, feats_bf, Wk_bf,
                                             b_q, b_k, g_q, g_k, qkss, QKbuf, Vt);
    // 3) fused attention (applies rs_q / rs_n from qkss)
    attn_kernel<<<dim3(128, 4), 512, 0, stream>>>(QKbuf, QKbuf + 4096 * 1024, Vt, qkss, attn_bf);
    // 4) O-projection -> fp32 d_out
    gemm_o_kernel<<<512, 256, 0, stream>>>(attn_bf, Wo_bf, b_o, (float*)d_out);
}